// Round 19
// baseline (36.838 us; speedup 1.0000x reference)
//
#include <hip/hip_runtime.h>

// CRF NLL forward, B=8192, L=512, T=6 (4 real states + START/STOP).
// 64-lane wave = 2 batches x 32 lanes; dynamic wave-uniform segmentation
// (seg2 = ceil(max(len)/32) rounded even; guarded pair groups skip compute
// AND fetch for short sequences). Scaled-probability domain, pow2 renorm,
// exponent in int. Combine: 4 ordered __shfl_down rounds width 32 (renorm
// after k=2,8) + final k=16 rank-1 mat-vec. Gold fused per-lane.
// R19 = R14 body at the proven (256,4) tier [(256,5)/(256,6)/(256,8) all
// spill: 9.4/28/50 MB scratch], + R18's prologue reorder, + the final
// reduction FUSED: per-block LDS reduce + one atomicAdd per block
// (eliminates the k_reduce dispatch + gap, ~3-4 us of the 32.2).

#define BB 8192
#define LL 512
#define LN2F 0.69314718055994530942f

__device__ __forceinline__ float uniformf(float x) {
    return __uint_as_float(__builtin_amdgcn_readfirstlane(__float_as_uint(x)));
}

#define RENORM16(P, MEX)                                                \
  do {                                                                  \
    float m_ = fmaxf(P[0], P[1]);                                       \
    _Pragma("unroll") for (int z_ = 2; z_ < 16; ++z_) m_ = fmaxf(m_, P[z_]); \
    const int ee_ = (int)((__float_as_uint(m_) >> 23) & 255) - 127;     \
    const float sc_ = __uint_as_float((unsigned)(127 - ee_) << 23);     \
    _Pragma("unroll") for (int z_ = 0; z_ < 16; ++z_) P[z_] *= sc_;     \
    MEX += ee_;                                                         \
  } while (0)

// One step at relative index S: P <- diag(exp(f)) * E * P (masked), + gold.
#define STEP(S, F0, F1, F2, F3, TG, PV)                                 \
  do {                                                                  \
    const bool act_ = (base + (S)) < len;                               \
    const float f0_=(F0), f1_=(F1), f2_=(F2), f3_=(F3);                 \
    const float fe0_=__expf(f0_), fe1_=__expf(f1_);                     \
    const float fe2_=__expf(f2_), fe3_=__expf(f3_);                     \
    _Pragma("unroll")                                                   \
    for (int j = 0; j < 4; ++j) {                                       \
      const float c0_=P[0*4+j], c1_=P[1*4+j], c2_=P[2*4+j], c3_=P[3*4+j]; \
      const float t0_ = fmaf(E[0], c0_, fmaf(E[1], c1_, fmaf(E[2], c2_, E[3] *c3_))); \
      const float t1_ = fmaf(E[4], c0_, fmaf(E[5], c1_, fmaf(E[6], c2_, E[7] *c3_))); \
      const float t2_ = fmaf(E[8], c0_, fmaf(E[9], c1_, fmaf(E[10],c2_, E[11]*c3_))); \
      const float t3_ = fmaf(E[12],c0_, fmaf(E[13],c1_, fmaf(E[14],c2_, E[15]*c3_))); \
      P[0*4+j] = act_ ? fe0_*t0_ : P[0*4+j];                            \
      P[1*4+j] = act_ ? fe1_*t1_ : P[1*4+j];                            \
      P[2*4+j] = act_ ? fe2_*t2_ : P[2*4+j];                            \
      P[3*4+j] = act_ ? fe3_*t3_ : P[3*4+j];                            \
    }                                                                   \
    const float lut_ = sT[(TG) * 6 + (PV)];                             \
    const float em_  = ((TG) & 2) ? (((TG) & 1) ? f3_ : f2_)            \
                                  : (((TG) & 1) ? f1_ : f0_);           \
    gold += act_ ? (lut_ + em_) : 0.f;                                  \
  } while (0)

#define TGAT(S)  ((int)((tpk >> (2*(S))) & 3u))
#define STEPE(S) STEP((S), F0[(S)/2].x, F0[(S)/2].y, F0[(S)/2].z, F0[(S)/2].w, TGAT(S), TGAT((S)-1))
#define STEPO(S) STEP((S), F1[(S)/2].x, F1[(S)/2].y, F2[(S)/2].x, F2[(S)/2].y, TGAT(S), TGAT((S)-1))

__global__ __launch_bounds__(256, 4) void crf_tree(
    const float* __restrict__ feats,
    const float* __restrict__ trans,
    const int*   __restrict__ tags,
    const int*   __restrict__ lens,
    float* __restrict__ out)
{
    __shared__ float sT[36];
    __shared__ float sRed[8];

    const int tid  = threadIdx.x;
    const int lane = tid & 63;
    const int wv   = tid >> 6;
    const int g    = lane >> 5;        // batch sub-index within wave (0..1)
    const int c    = lane & 31;        // segment index (0..31)
    const int b    = blockIdx.x * 8 + wv * 2 + g;

    const int len = lens[b];           // issue first
    if (tid < 36) sT[tid] = trans[tid];
    __syncthreads();

    // dynamic wave-uniform segment size: covers max(len) of both batches
    const int wmax  = max(len, __shfl_xor(len, 32, 64));
    const int seg2  = __builtin_amdgcn_readfirstlane(((wmax + 31) >> 5) + 1) & ~1;
    const int npair = __builtin_amdgcn_readfirstlane(seg2 >> 1);   // 1..8
    const int base  = c * seg2;
    const bool seg0 = (c == 0);

    const float* fp  = feats + (size_t)b * (LL * 6) + (size_t)base * 6;
    const int*   tbp = tags  + (size_t)b * LL + base;
    const int pv0 = seg0 ? 4 : (tbp[-1] & 3);

    // ---- guarded up-front loads BEFORE E setup (latency hides under it) ----
    float4 F0[8]; float2 F1[8], F2[8];
    #pragma unroll
    for (int p = 0; p < 8; ++p)
        if (p < npair) {
            const float* q = fp + p * 12;
            F0[p] = *(const float4*)(q);
            F1[p] = *(const float2*)(q + 6);
            F2[p] = *(const float2*)(q + 8);
        }
    unsigned tpk = 0;                      // seg2 tags packed 2b each
    #pragma unroll
    for (int q = 0; q < 4; ++q)
        if (q * 4 < seg2) {
            const int4 t = *(const int4*)(tbp + q * 4);
            tpk |= (unsigned)(t.x & 3) << (2*(q*4+0));
            tpk |= (unsigned)(t.y & 3) << (2*(q*4+1));
            tpk |= (unsigned)(t.z & 3) << (2*(q*4+2));
            tpk |= (unsigned)(t.w & 3) << (2*(q*4+3));
        }

    // ---- wave-uniform transition constants (SGPR via readfirstlane) ----
    float E[16], e4[4], e5[4];
    #pragma unroll
    for (int i = 0; i < 16; ++i)
        E[i] = uniformf(__expf(sT[(i >> 2) * 6 + (i & 3)]));
    #pragma unroll
    for (int i = 0; i < 4; ++i) {
        e4[i] = uniformf(__expf(sT[i * 6 + 4]));   // exp(trans[i][START])
        e5[i] = uniformf(__expf(sT[30 + i]));      // exp(trans[STOP][i])
    }

    float P[16];
    #pragma unroll
    for (int z = 0; z < 16; ++z) P[z] = (z % 5 == 0) ? 1.f : 0.f;
    int   mex  = 0;
    float gold = 0.f;

    // ---- step 0 specialized: P was identity; seg0 folds e4 (START) ----
    {
        const bool act_ = base < len;
        const float f0_=F0[0].x, f1_=F0[0].y, f2_=F0[0].z, f3_=F0[0].w;
        const float fe0_=__expf(f0_), fe1_=__expf(f1_);
        const float fe2_=__expf(f2_), fe3_=__expf(f3_);
        #pragma unroll
        for (int j = 0; j < 4; ++j) {
            const float u0 = seg0 ? e4[0] : E[0*4+j];
            const float u1 = seg0 ? e4[1] : E[1*4+j];
            const float u2 = seg0 ? e4[2] : E[2*4+j];
            const float u3 = seg0 ? e4[3] : E[3*4+j];
            P[0*4+j] = act_ ? fe0_*u0 : P[0*4+j];
            P[1*4+j] = act_ ? fe1_*u1 : P[1*4+j];
            P[2*4+j] = act_ ? fe2_*u2 : P[2*4+j];
            P[3*4+j] = act_ ? fe3_*u3 : P[3*4+j];
        }
        const int t0 = TGAT(0);
        const float lut_ = sT[t0 * 6 + pv0];
        const float em_  = (t0 & 2) ? ((t0 & 1) ? f3_ : f2_)
                                    : ((t0 & 1) ? f1_ : f0_);
        gold += act_ ? (lut_ + em_) : 0.f;
        STEP(1, F1[0].x, F1[0].y, F2[0].x, F2[0].y, TGAT(1), t0);
    }
    if (npair > 1) { STEPE(2);  STEPO(3);  RENORM16(P, mex); }
    if (npair > 2) { STEPE(4);  STEPO(5);  }
    if (npair > 3) { STEPE(6);  STEPO(7);  RENORM16(P, mex); }
    if (npair > 4) { STEPE(8);  STEPO(9);  }
    if (npair > 5) { STEPE(10); STEPO(11); RENORM16(P, mex); }
    if (npair > 6) { STEPE(12); STEPO(13); }
    if (npair > 7) { STEPE(14); STEPO(15); RENORM16(P, mex); }

    // terminal gold: lane owning step len-1 adds trans[STOP][last_tag]
    {
        const unsigned dl = (unsigned)(len - 1 - base);
        if (dl < (unsigned)seg2) gold += sT[30 + (int)((tpk >> (2*dl)) & 3u)];
    }

    // ---- ordered combine width 32: P <- P_{c+k} * P_c, k=1,2,4,8 ----
    #pragma unroll
    for (int k = 1; k <= 8; k <<= 1) {
        float Q[16];
        #pragma unroll
        for (int z = 0; z < 16; ++z) Q[z] = __shfl_down(P[z], k, 32);
        const int mq = __shfl_down(mex, k, 32);
        float N[16];
        #pragma unroll
        for (int i = 0; i < 4; ++i)
            #pragma unroll
            for (int j = 0; j < 4; ++j)
                N[i*4+j] = fmaf(Q[i*4+0], P[0*4+j], fmaf(Q[i*4+1], P[1*4+j],
                           fmaf(Q[i*4+2], P[2*4+j], Q[i*4+3] * P[3*4+j])));
        #pragma unroll
        for (int z = 0; z < 16; ++z) P[z] = N[z];
        mex += mq;
        if (k == 2 || k == 8) RENORM16(P, mex);
    }

    // ---- final k=16: rank-1 -> mat-vec (alpha = column 0) ----
    float al0, al1, al2, al3;
    {
        float Q[16];
        #pragma unroll
        for (int z = 0; z < 16; ++z) Q[z] = __shfl_down(P[z], 16, 32);
        const int mq = __shfl_down(mex, 16, 32);
        al0 = fmaf(Q[0], P[0], fmaf(Q[1], P[4], fmaf(Q[2], P[8], Q[3] *P[12])));
        al1 = fmaf(Q[4], P[0], fmaf(Q[5], P[4], fmaf(Q[6], P[8], Q[7] *P[12])));
        al2 = fmaf(Q[8], P[0], fmaf(Q[9], P[4], fmaf(Q[10],P[8], Q[11]*P[12])));
        al3 = fmaf(Q[12],P[0], fmaf(Q[13],P[4], fmaf(Q[14],P[8], Q[15]*P[12])));
        mex += mq;
    }

    // gold: sum across the 32-lane group
    #pragma unroll
    for (int k = 1; k <= 16; k <<= 1)
        gold += __shfl_xor(gold, k, 32);

    const float dot = fmaf(e5[0], al0, fmaf(e5[1], al1,
                      fmaf(e5[2], al2, e5[3] * al3)));
    const float logz = fmaf((float)mex, LN2F, __logf(dot));

    // ---- fused finish: per-block reduce + one atomicAdd per block ----
    if (c == 0) sRed[wv * 2 + g] = logz - gold;
    __syncthreads();
    if (tid == 0) {
        float s = 0.f;
        #pragma unroll
        for (int j = 0; j < 8; ++j) s += sRed[j];
        atomicAdd(out, s * (1.0f / 8192.0f));
    }
}

extern "C" void kernel_launch(void* const* d_in, const int* in_sizes, int n_in,
                              void* d_out, int out_size, void* d_ws, size_t ws_size,
                              hipStream_t stream) {
    const float* feats = (const float*)d_in[0];
    const float* trans = (const float*)d_in[1];
    const int*   tags  = (const int*)d_in[2];
    const int*   lens  = (const int*)d_in[3];
    float* out = (float*)d_out;

    hipMemsetAsync(out, 0, sizeof(float) * out_size, stream);
    crf_tree<<<BB / 8, 256, 0, stream>>>(feats, trans, tags, lens, out);
}

// Round 20
// 31.850 us; speedup vs baseline: 1.1566x; 1.1566x over previous
//
#include <hip/hip_runtime.h>

// CRF NLL forward, B=8192, L=512, T=6 (4 real states + START/STOP).
// 64-lane wave = 2 batches x 32 lanes. Lane (g,c) builds the ordered product
// of M_l = diag(exp(feat_l)) * E over steps [16c, 16c+16) of batch g
// (scaled-probability domain, power-of-2 renorm every 4 steps, exponent in an
// int). ALL 24 feat loads + tags issued up front (MLP). Combine: 4 ordered
// __shfl_down rounds at width=32 (k=1,2,4,8; renorm after k=2,8 only) +
// final k=16 rank-1 mat-vec (segment-0 e4 fold makes lane 0's columns all
// equal alpha). Gold fused per-lane, shfl_xor width-32 reduced.
// FINAL (R20) = exact revert to R13, the session's best measured kernel
// (32.16 us; R14's dynamic-seg twin 32.18). Session evidence: (256,5/6/8)
// all spill (9.4/28/50 MB scratch; natural VGPR >102 -> 4 waves/SIMD is the
// only clean tier); JIT loads -4us; rotating pipeline spills; -30% inst /
// -27% bytes nulls at this occupancy (latency-bound); fused-atomic finish
// -4.6us (block-end barrier couples waves, kills early retire).

#define BB 8192
#define LL 512
#define LN2F 0.69314718055994530942f

__device__ __forceinline__ float uniformf(float x) {
    return __uint_as_float(__builtin_amdgcn_readfirstlane(__float_as_uint(x)));
}

#define RENORM16(P, MEX)                                                \
  do {                                                                  \
    float m_ = fmaxf(P[0], P[1]);                                       \
    _Pragma("unroll") for (int z_ = 2; z_ < 16; ++z_) m_ = fmaxf(m_, P[z_]); \
    const int ee_ = (int)((__float_as_uint(m_) >> 23) & 255) - 127;     \
    const float sc_ = __uint_as_float((unsigned)(127 - ee_) << 23);     \
    _Pragma("unroll") for (int z_ = 0; z_ < 16; ++z_) P[z_] *= sc_;     \
    MEX += ee_;                                                         \
  } while (0)

// One step at absolute index ABS: P <- diag(exp(f)) * E * P (masked), + gold.
#define STEP(ABS, F0, F1, F2, F3, TG, PV)                               \
  do {                                                                  \
    const bool act_ = (ABS) < len;                                      \
    const float f0_=(F0), f1_=(F1), f2_=(F2), f3_=(F3);                 \
    const float fe0_=__expf(f0_), fe1_=__expf(f1_);                     \
    const float fe2_=__expf(f2_), fe3_=__expf(f3_);                     \
    _Pragma("unroll")                                                   \
    for (int j = 0; j < 4; ++j) {                                       \
      const float c0_=P[0*4+j], c1_=P[1*4+j], c2_=P[2*4+j], c3_=P[3*4+j]; \
      const float t0_ = fmaf(E[0], c0_, fmaf(E[1], c1_, fmaf(E[2], c2_, E[3] *c3_))); \
      const float t1_ = fmaf(E[4], c0_, fmaf(E[5], c1_, fmaf(E[6], c2_, E[7] *c3_))); \
      const float t2_ = fmaf(E[8], c0_, fmaf(E[9], c1_, fmaf(E[10],c2_, E[11]*c3_))); \
      const float t3_ = fmaf(E[12],c0_, fmaf(E[13],c1_, fmaf(E[14],c2_, E[15]*c3_))); \
      P[0*4+j] = act_ ? fe0_*t0_ : P[0*4+j];                            \
      P[1*4+j] = act_ ? fe1_*t1_ : P[1*4+j];                            \
      P[2*4+j] = act_ ? fe2_*t2_ : P[2*4+j];                            \
      P[3*4+j] = act_ ? fe3_*t3_ : P[3*4+j];                            \
    }                                                                   \
    const float lut_ = sT[(TG) * 6 + (PV)];                             \
    const float em_  = ((TG) & 2) ? (((TG) & 1) ? f3_ : f2_)            \
                                  : (((TG) & 1) ? f1_ : f0_);           \
    gold += act_ ? (lut_ + em_) : 0.f;                                  \
  } while (0)

// step s (1..15): even s uses F0[s/2]; odd s uses F1[s/2],F2[s/2]
#define TGAT(S)  ((int)((tpk >> (2*(S))) & 3u))
#define STEPE(S) STEP(base+(S), F0[(S)/2].x, F0[(S)/2].y, F0[(S)/2].z, F0[(S)/2].w, TGAT(S), TGAT((S)-1))
#define STEPO(S) STEP(base+(S), F1[(S)/2].x, F1[(S)/2].y, F2[(S)/2].x, F2[(S)/2].y, TGAT(S), TGAT((S)-1))

__global__ __launch_bounds__(256, 4) void crf_tree(
    const float* __restrict__ feats,
    const float* __restrict__ trans,
    const int*   __restrict__ tags,
    const int*   __restrict__ lens,
    float* __restrict__ partials)
{
    __shared__ float sT[36];

    const int tid  = threadIdx.x;
    const int lane = tid & 63;
    const int wv   = tid >> 6;
    const int g    = lane >> 5;        // batch sub-index within wave (0..1)
    const int c    = lane & 31;        // segment index (0..31), 16 steps each
    const int b    = blockIdx.x * 8 + wv * 2 + g;

    if (tid < 36) sT[tid] = trans[tid];
    __syncthreads();

    // wave-uniform transition constants (SGPR via readfirstlane)
    float E[16], e4[4], e5[4];
    #pragma unroll
    for (int i = 0; i < 16; ++i)
        E[i] = uniformf(__expf(sT[(i >> 2) * 6 + (i & 3)]));
    #pragma unroll
    for (int i = 0; i < 4; ++i) {
        e4[i] = uniformf(__expf(sT[i * 6 + 4]));   // exp(trans[i][START])
        e5[i] = uniformf(__expf(sT[30 + i]));      // exp(trans[STOP][i])
    }

    const int len  = lens[b];
    const int base = c * 16;
    const bool seg0 = (c == 0);

    const float* fp  = feats + (size_t)b * (LL * 6) + (size_t)base * 6;
    const int*   tbp = tags  + (size_t)b * LL + base;
    const int pv0 = seg0 ? 4 : (tbp[-1] & 3);

    // ---- ALL loads issued up front (24 feat + 4 tag loads in flight) ----
    float4 F0[8]; float2 F1[8], F2[8];
    #pragma unroll
    for (int p = 0; p < 8; ++p) {
        const float* q = fp + p * 12;
        F0[p] = *(const float4*)(q);
        F1[p] = *(const float2*)(q + 6);
        F2[p] = *(const float2*)(q + 8);
    }
    unsigned tpk = 0;                      // 16 tags packed 2b each
    #pragma unroll
    for (int q = 0; q < 4; ++q) {
        const int4 t = *(const int4*)(tbp + q * 4);
        tpk |= (unsigned)(t.x & 3) << (2*(q*4+0));
        tpk |= (unsigned)(t.y & 3) << (2*(q*4+1));
        tpk |= (unsigned)(t.z & 3) << (2*(q*4+2));
        tpk |= (unsigned)(t.w & 3) << (2*(q*4+3));
    }

    float P[16];
    #pragma unroll
    for (int z = 0; z < 16; ++z) P[z] = (z % 5 == 0) ? 1.f : 0.f;
    int   mex  = 0;
    float gold = 0.f;

    // ---- step 0 specialized: P was identity; seg0 folds e4 (START) ----
    {
        const bool act_ = base < len;
        const float f0_=F0[0].x, f1_=F0[0].y, f2_=F0[0].z, f3_=F0[0].w;
        const float fe0_=__expf(f0_), fe1_=__expf(f1_);
        const float fe2_=__expf(f2_), fe3_=__expf(f3_);
        #pragma unroll
        for (int j = 0; j < 4; ++j) {
            const float u0 = seg0 ? e4[0] : E[0*4+j];
            const float u1 = seg0 ? e4[1] : E[1*4+j];
            const float u2 = seg0 ? e4[2] : E[2*4+j];
            const float u3 = seg0 ? e4[3] : E[3*4+j];
            P[0*4+j] = act_ ? fe0_*u0 : P[0*4+j];
            P[1*4+j] = act_ ? fe1_*u1 : P[1*4+j];
            P[2*4+j] = act_ ? fe2_*u2 : P[2*4+j];
            P[3*4+j] = act_ ? fe3_*u3 : P[3*4+j];
        }
        const int t0 = TGAT(0);
        const float lut_ = sT[t0 * 6 + pv0];
        const float em_  = (t0 & 2) ? ((t0 & 1) ? f3_ : f2_)
                                    : ((t0 & 1) ? f1_ : f0_);
        gold += act_ ? (lut_ + em_) : 0.f;
    }
    STEPO(1);  STEPE(2);  STEPO(3);  RENORM16(P, mex);
    STEPE(4);  STEPO(5);  STEPE(6);  STEPO(7);  RENORM16(P, mex);
    STEPE(8);  STEPO(9);  STEPE(10); STEPO(11); RENORM16(P, mex);
    STEPE(12); STEPO(13); STEPE(14); STEPO(15); RENORM16(P, mex);

    // terminal gold: lane owning step len-1 adds trans[STOP][last_tag]
    {
        const unsigned dl = (unsigned)(len - 1 - base);
        if (dl < 16u) gold += sT[30 + (int)((tpk >> (2*dl)) & 3u)];
    }

    // ---- ordered combine width 32: P <- P_{c+k} * P_c, k=1,2,4,8 ----
    // renorm only after k=2 and k=8 (growth <= 2^10 between; exact pow2)
    #pragma unroll
    for (int k = 1; k <= 8; k <<= 1) {
        float Q[16];
        #pragma unroll
        for (int z = 0; z < 16; ++z) Q[z] = __shfl_down(P[z], k, 32);
        const int mq = __shfl_down(mex, k, 32);
        float N[16];
        #pragma unroll
        for (int i = 0; i < 4; ++i)
            #pragma unroll
            for (int j = 0; j < 4; ++j)
                N[i*4+j] = fmaf(Q[i*4+0], P[0*4+j], fmaf(Q[i*4+1], P[1*4+j],
                           fmaf(Q[i*4+2], P[2*4+j], Q[i*4+3] * P[3*4+j])));
        #pragma unroll
        for (int z = 0; z < 16; ++z) P[z] = N[z];
        mex += mq;
        if (k == 2 || k == 8) RENORM16(P, mex);
    }

    // ---- final k=16: rank-1 -> mat-vec (alpha = column 0) ----
    float al0, al1, al2, al3;
    {
        float Q[16];
        #pragma unroll
        for (int z = 0; z < 16; ++z) Q[z] = __shfl_down(P[z], 16, 32);
        const int mq = __shfl_down(mex, 16, 32);
        al0 = fmaf(Q[0], P[0], fmaf(Q[1], P[4], fmaf(Q[2], P[8], Q[3] *P[12])));
        al1 = fmaf(Q[4], P[0], fmaf(Q[5], P[4], fmaf(Q[6], P[8], Q[7] *P[12])));
        al2 = fmaf(Q[8], P[0], fmaf(Q[9], P[4], fmaf(Q[10],P[8], Q[11]*P[12])));
        al3 = fmaf(Q[12],P[0], fmaf(Q[13],P[4], fmaf(Q[14],P[8], Q[15]*P[12])));
        mex += mq;
    }

    // gold: sum across the 32-lane group
    #pragma unroll
    for (int k = 1; k <= 16; k <<= 1)
        gold += __shfl_xor(gold, k, 32);

    const float dot = fmaf(e5[0], al0, fmaf(e5[1], al1,
                      fmaf(e5[2], al2, e5[3] * al3)));
    const float logz = fmaf((float)mex, LN2F, __logf(dot));
    if (c == 0)
        partials[b] = logz - gold;
}

__global__ __launch_bounds__(256) void k_reduce(const float* __restrict__ partials,
                                               float* __restrict__ out)
{
    __shared__ float sh[256];
    const int t = threadIdx.x;
    float s = 0.f;
    #pragma unroll
    for (int j = 0; j < 32; ++j) s += partials[t + 256 * j];
    sh[t] = s;
    __syncthreads();
    #pragma unroll
    for (int d = 128; d > 0; d >>= 1) {
        if (t < d) sh[t] += sh[t + d];
        __syncthreads();
    }
    if (t == 0) out[0] = sh[0] * (1.0f / 8192.0f);
}

extern "C" void kernel_launch(void* const* d_in, const int* in_sizes, int n_in,
                              void* d_out, int out_size, void* d_ws, size_t ws_size,
                              hipStream_t stream) {
    const float* feats = (const float*)d_in[0];
    const float* trans = (const float*)d_in[1];
    const int*   tags  = (const int*)d_in[2];
    const int*   lens  = (const int*)d_in[3];
    float* out = (float*)d_out;
    float* partials = (float*)d_ws;        // 8192 floats

    crf_tree<<<BB / 8, 256, 0, stream>>>(feats, trans, tags, lens, partials);
    k_reduce<<<1, 256, 0, stream>>>(partials, out);
}